// Round 2
// baseline (239.393 us; speedup 1.0000x reference)
//
#include <hip/hip_runtime.h>
#include <stdint.h>

typedef __bf16 bf16x8 __attribute__((ext_vector_type(8)));
typedef float f32x4 __attribute__((ext_vector_type(4)));
typedef unsigned short ushort8v __attribute__((ext_vector_type(8)));

static constexpr int SUBSETS = 3;
static constexpr int M = 4096;
static constexpr int D = 128;

#define MARGIN_F 0.1f
#define NEGINF (-1e30f)

// ---------------- kernel 0: f32 -> bf16 (RNE) ----------------
__global__ void cvt_f32_bf16(const float* __restrict__ in,
                             unsigned short* __restrict__ out, int n8) {
    int i = blockIdx.x * blockDim.x + threadIdx.x;
    if (i >= n8) return;
    const float4* p = reinterpret_cast<const float4*>(in) + (size_t)i * 2;
    float4 a = p[0];
    float4 b = p[1];
    float v[8] = {a.x, a.y, a.z, a.w, b.x, b.y, b.z, b.w};
    ushort8v r;
#pragma unroll
    for (int j = 0; j < 8; ++j) {
        uint32_t u = __builtin_bit_cast(uint32_t, v[j]);
        u = (u + 0x7FFFu + ((u >> 16) & 1u)) >> 16;  // round-nearest-even to bf16
        r[j] = (unsigned short)u;
    }
    *(reinterpret_cast<ushort8v*>(out) + i) = r;
}

// ---------------- kernel 1: fused two-phase triplet loss ----------------
// grid = 3 subsets * 256 row-blocks (16 rows each); 256 threads = 4 waves;
// each wave covers a 1024-column strip. Phase 1: masked row maxes.
// Phase 2: recompute sim, thresholded sums. One atomicAdd per WG.
__global__ __launch_bounds__(256) void triplet_fused(
        const unsigned short* __restrict__ ebf,
        const int* __restrict__ tgt,
        float* __restrict__ out) {
    const int wg = blockIdx.x;
    const int subset = wg >> 8;
    const int rowBase = (wg & 255) * 16;
    const unsigned short* E = ebf + (size_t)subset * M * D;
    const int* T = tgt + subset * M;

    const int tid = threadIdx.x;
    const int wave = tid >> 6;
    const int lane = tid & 63;
    const int lhi = lane >> 4;   // 0..3
    const int llo = lane & 15;   // 0..15

    __shared__ float smaxp[4][16];
    __shared__ float smaxn[4][16];
    __shared__ float ssum[4][16];

    // A fragments: 16 rows x 128 k, lane holds row llo, k = kb*32 + lhi*8 + j
    bf16x8 afrag[4];
    {
        const int arow = rowBase + llo;
#pragma unroll
        for (int kb = 0; kb < 4; ++kb)
            afrag[kb] = *reinterpret_cast<const bf16x8*>(
                E + (size_t)arow * D + kb * 32 + lhi * 8);
    }
    // targets of the 4 C-rows this lane owns (row = lhi*4 + r)
    int trow[4];
#pragma unroll
    for (int r = 0; r < 4; ++r) trow[r] = T[rowBase + lhi * 4 + r];

    const int colStart = wave * (M / 4);
    const int NT = (M / 4) / 16;  // 64 column tiles per wave

    // ---------- phase 1: maxes ----------
    float maxp[4], maxn[4];
#pragma unroll
    for (int r = 0; r < 4; ++r) { maxp[r] = NEGINF; maxn[r] = NEGINF; }

    for (int t = 0; t < NT; ++t) {
        const int colBase = colStart + t * 16;
        const int bcol = colBase + llo;
        bf16x8 bfrag[4];
#pragma unroll
        for (int kb = 0; kb < 4; ++kb)
            bfrag[kb] = *reinterpret_cast<const bf16x8*>(
                E + (size_t)bcol * D + kb * 32 + lhi * 8);
        f32x4 acc = {0.f, 0.f, 0.f, 0.f};
#pragma unroll
        for (int kb = 0; kb < 4; ++kb)
            acc = __builtin_amdgcn_mfma_f32_16x16x32_bf16(afrag[kb], bfrag[kb], acc, 0, 0, 0);
        const int tcol = T[bcol];  // C col of this lane = colBase + llo
        const int colG = bcol;
#pragma unroll
        for (int r = 0; r < 4; ++r) {
            const float s = acc[r];
            const int rowG = rowBase + lhi * 4 + r;
            if (tcol == trow[r]) {
                if (rowG != colG) maxp[r] = fmaxf(maxp[r], s);
            } else {
                maxn[r] = fmaxf(maxn[r], s);
            }
        }
    }
    // reduce maxes over the 16 lanes (llo) that share each C-row
#pragma unroll
    for (int r = 0; r < 4; ++r) {
#pragma unroll
        for (int off = 1; off < 16; off <<= 1) {
            maxp[r] = fmaxf(maxp[r], __shfl_xor(maxp[r], off));
            maxn[r] = fmaxf(maxn[r], __shfl_xor(maxn[r], off));
        }
    }
    if (llo == 0) {
#pragma unroll
        for (int r = 0; r < 4; ++r) {
            smaxp[wave][lhi * 4 + r] = maxp[r];
            smaxn[wave][lhi * 4 + r] = maxn[r];
        }
    }
    __syncthreads();

    float thrP[4], thrN[4];
#pragma unroll
    for (int r = 0; r < 4; ++r) {
        const int row = lhi * 4 + r;
        const float mp = fmaxf(fmaxf(smaxp[0][row], smaxp[1][row]),
                               fmaxf(smaxp[2][row], smaxp[3][row]));
        const float mn = fmaxf(fmaxf(smaxn[0][row], smaxn[1][row]),
                               fmaxf(smaxn[2][row], smaxn[3][row]));
        thrP[r] = mn + MARGIN_F;                 // pos selected if sim < thrP
        thrN[r] = fmaxf(0.6f, mp) - MARGIN_F;    // neg selected if sim > thrN
    }

    // ---------- phase 2: thresholded sums (recompute sim) ----------
    float acl[4] = {0.f, 0.f, 0.f, 0.f};
    for (int t = 0; t < NT; ++t) {
        const int colBase = colStart + t * 16;
        const int bcol = colBase + llo;
        bf16x8 bfrag[4];
#pragma unroll
        for (int kb = 0; kb < 4; ++kb)
            bfrag[kb] = *reinterpret_cast<const bf16x8*>(
                E + (size_t)bcol * D + kb * 32 + lhi * 8);
        f32x4 acc = {0.f, 0.f, 0.f, 0.f};
#pragma unroll
        for (int kb = 0; kb < 4; ++kb)
            acc = __builtin_amdgcn_mfma_f32_16x16x32_bf16(afrag[kb], bfrag[kb], acc, 0, 0, 0);
        const int tcol = T[bcol];
        const int colG = bcol;
#pragma unroll
        for (int r = 0; r < 4; ++r) {
            const float s = acc[r];
            const int rowG = rowBase + lhi * 4 + r;
            if (tcol == trow[r]) {
                if (rowG != colG && s < thrP[r]) acl[r] += 1.0f - s;
            } else {
                if (s > thrN[r]) acl[r] += s;
            }
        }
    }
#pragma unroll
    for (int r = 0; r < 4; ++r) {
#pragma unroll
        for (int off = 1; off < 16; off <<= 1)
            acl[r] += __shfl_xor(acl[r], off);
    }
    if (llo == 0) {
#pragma unroll
        for (int r = 0; r < 4; ++r) ssum[wave][lhi * 4 + r] = acl[r];
    }
    __syncthreads();

    if (wave == 0) {
        float v = 0.f;
        if (lane < 16) {
            const float mp = fmaxf(fmaxf(smaxp[0][lane], smaxp[1][lane]),
                                   fmaxf(smaxp[2][lane], smaxp[3][lane]));
            if (mp > -1e29f)  // has_pos
                v = ssum[0][lane] + ssum[1][lane] + ssum[2][lane] + ssum[3][lane];
        }
#pragma unroll
        for (int off = 1; off < 16; off <<= 1) v += __shfl_xor(v, off);
        if (lane == 0) atomicAdd(out, v * (1.0f / 12288.0f));
    }
}

extern "C" void kernel_launch(void* const* d_in, const int* in_sizes, int n_in,
                              void* d_out, int out_size, void* d_ws, size_t ws_size,
                              hipStream_t stream) {
    const float* emb = (const float*)d_in[0];
    const int* tgt = (const int*)d_in[1];
    float* out = (float*)d_out;
    unsigned short* ebf = (unsigned short*)d_ws;  // 3*4096*128 bf16 = 3 MiB

    const int n = SUBSETS * M * D;   // 1,572,864 floats
    const int n8 = n / 8;            // 196,608

    hipMemsetAsync(out, 0, sizeof(float), stream);
    cvt_f32_bf16<<<n8 / 256, 256, 0, stream>>>(emb, ebf, n8);
    triplet_fused<<<SUBSETS * 256, 256, 0, stream>>>(ebf, tgt, out);
}

// Round 4
// 187.181 us; speedup vs baseline: 1.2789x; 1.2789x over previous
//
#include <hip/hip_runtime.h>
#include <stdint.h>

typedef __bf16 bf16x8 __attribute__((ext_vector_type(8)));
typedef float f32x4 __attribute__((ext_vector_type(4)));
typedef unsigned short ushort8v __attribute__((ext_vector_type(8)));

static constexpr int SUBSETS = 3;
static constexpr int M = 4096;
static constexpr int D = 128;

static constexpr int RPW = 32;              // rows per wave (2 MFMA row-blocks)
static constexpr int CPW = 256;             // cols per wave
static constexpr int NSTRIP = M / CPW;      // 16 column strips
static constexpr int NRB = M / RPW;         // 128 row blocks
static constexpr int WAVES = SUBSETS * NRB * NSTRIP;  // 6144
static constexpr int WGS = WAVES / 4;                 // 1536

#define MARGIN_F 0.1f
#define NEGINF (-1e30f)

// ---------------- kernel 0: f32 -> bf16 (RNE) ----------------
__global__ void cvt_f32_bf16(const float* __restrict__ in,
                             unsigned short* __restrict__ out, int n8) {
    int i = blockIdx.x * blockDim.x + threadIdx.x;
    if (i >= n8) return;
    const float4* p = reinterpret_cast<const float4*>(in) + (size_t)i * 2;
    float4 a = p[0];
    float4 b = p[1];
    float v[8] = {a.x, a.y, a.z, a.w, b.x, b.y, b.z, b.w};
    ushort8v r;
#pragma unroll
    for (int j = 0; j < 8; ++j) {
        uint32_t u = __builtin_bit_cast(uint32_t, v[j]);
        u = (u + 0x7FFFu + ((u >> 16) & 1u)) >> 16;  // RNE to bf16
        r[j] = (unsigned short)u;
    }
    *(reinterpret_cast<ushort8v*>(out) + i) = r;
}

// Common per-wave geometry:
//   gwid = blockIdx.x*4 + wave; s = gwid/2048; rem = gwid%2048
//   rb = rem & 127 (row block of 32 rows), cs = rem >> 7 (256-col strip)
//   -> consecutive waves (one WG) share cs => B tiles shared in L1.

// ---------------- kernel 1: masked row maxes (pass 1) ----------------
__global__ __launch_bounds__(256) void pass_max(
        const unsigned short* __restrict__ ebf,
        const int* __restrict__ tgt,
        float* __restrict__ wsmax) {   // [2][SUBSETS][M][NSTRIP]
    const int gwid = blockIdx.x * 4 + (threadIdx.x >> 6);
    const int lane = threadIdx.x & 63;
    const int s = gwid >> 11;
    const int rem = gwid & 2047;
    const int rb = rem & (NRB - 1);
    const int cs = rem >> 7;

    const unsigned short* E = ebf + (size_t)s * M * D;
    const int* T = tgt + s * M;
    const int lhi = lane >> 4, llo = lane & 15;
    const int rowBase = rb * RPW;
    const int colBase0 = cs * CPW;

    bf16x8 a[2][4];
#pragma unroll
    for (int rr = 0; rr < 2; ++rr) {
        const int row = rowBase + rr * 16 + llo;
#pragma unroll
        for (int kb = 0; kb < 4; ++kb)
            a[rr][kb] = *reinterpret_cast<const bf16x8*>(
                E + (size_t)row * D + kb * 32 + lhi * 8);
    }
    int trow[2][4];
#pragma unroll
    for (int rr = 0; rr < 2; ++rr)
#pragma unroll
        for (int r = 0; r < 4; ++r)
            trow[rr][r] = T[rowBase + rr * 16 + lhi * 4 + r];

    float mp[2][4], mn[2][4];
#pragma unroll
    for (int rr = 0; rr < 2; ++rr)
#pragma unroll
        for (int r = 0; r < 4; ++r) { mp[rr][r] = NEGINF; mn[rr][r] = NEGINF; }

    for (int t = 0; t < CPW / 16; ++t) {
        const int bcol = colBase0 + t * 16 + llo;
        bf16x8 b[4];
#pragma unroll
        for (int kb = 0; kb < 4; ++kb)
            b[kb] = *reinterpret_cast<const bf16x8*>(
                E + (size_t)bcol * D + kb * 32 + lhi * 8);
        const int tcol = T[bcol];
#pragma unroll
        for (int rr = 0; rr < 2; ++rr) {
            f32x4 acc = {0.f, 0.f, 0.f, 0.f};
#pragma unroll
            for (int kb = 0; kb < 4; ++kb)
                acc = __builtin_amdgcn_mfma_f32_16x16x32_bf16(a[rr][kb], b[kb], acc, 0, 0, 0);
#pragma unroll
            for (int r = 0; r < 4; ++r) {
                const float sv = acc[r];
                const int rowG = rowBase + rr * 16 + lhi * 4 + r;
                if (tcol == trow[rr][r]) {
                    if (rowG != bcol) mp[rr][r] = fmaxf(mp[rr][r], sv);
                } else {
                    mn[rr][r] = fmaxf(mn[rr][r], sv);
                }
            }
        }
    }
#pragma unroll
    for (int rr = 0; rr < 2; ++rr)
#pragma unroll
        for (int r = 0; r < 4; ++r) {
#pragma unroll
            for (int off = 1; off < 16; off <<= 1) {
                mp[rr][r] = fmaxf(mp[rr][r], __shfl_xor(mp[rr][r], off));
                mn[rr][r] = fmaxf(mn[rr][r], __shfl_xor(mn[rr][r], off));
            }
        }
    if (llo == 0) {
#pragma unroll
        for (int rr = 0; rr < 2; ++rr)
#pragma unroll
            for (int r = 0; r < 4; ++r) {
                const int row = rowBase + rr * 16 + lhi * 4 + r;
                wsmax[((size_t)(0 * SUBSETS + s) * M + row) * NSTRIP + cs] = mp[rr][r];
                wsmax[((size_t)(1 * SUBSETS + s) * M + row) * NSTRIP + cs] = mn[rr][r];
            }
    }
}

// ---------------- kernel 2: thresholded sums (pass 2) ----------------
__global__ __launch_bounds__(256) void pass_sum(
        const unsigned short* __restrict__ ebf,
        const int* __restrict__ tgt,
        const float* __restrict__ wsmax,
        float* __restrict__ out) {
    const int gwid = blockIdx.x * 4 + (threadIdx.x >> 6);
    const int wave = threadIdx.x >> 6;
    const int lane = threadIdx.x & 63;
    const int s = gwid >> 11;
    const int rem = gwid & 2047;
    const int rb = rem & (NRB - 1);
    const int cs = rem >> 7;

    const unsigned short* E = ebf + (size_t)s * M * D;
    const int* T = tgt + s * M;
    const int lhi = lane >> 4, llo = lane & 15;
    const int rowBase = rb * RPW;
    const int colBase0 = cs * CPW;

    // thresholds from strip partials: lane llo reads strip llo, reduce over llo
    float thrP[2][4], thrN[2][4], hasPos[2][4];
#pragma unroll
    for (int rr = 0; rr < 2; ++rr)
#pragma unroll
        for (int r = 0; r < 4; ++r) {
            const int row = rowBase + rr * 16 + lhi * 4 + r;
            float vp = wsmax[((size_t)(0 * SUBSETS + s) * M + row) * NSTRIP + llo];
            float vn = wsmax[((size_t)(1 * SUBSETS + s) * M + row) * NSTRIP + llo];
#pragma unroll
            for (int off = 1; off < 16; off <<= 1) {
                vp = fmaxf(vp, __shfl_xor(vp, off));
                vn = fmaxf(vn, __shfl_xor(vn, off));
            }
            thrP[rr][r] = vn + MARGIN_F;
            thrN[rr][r] = fmaxf(0.6f, vp) - MARGIN_F;
            hasPos[rr][r] = (vp > -1e29f) ? 1.0f : 0.0f;
        }

    bf16x8 a[2][4];
#pragma unroll
    for (int rr = 0; rr < 2; ++rr) {
        const int row = rowBase + rr * 16 + llo;
#pragma unroll
        for (int kb = 0; kb < 4; ++kb)
            a[rr][kb] = *reinterpret_cast<const bf16x8*>(
                E + (size_t)row * D + kb * 32 + lhi * 8);
    }
    int trow[2][4];
#pragma unroll
    for (int rr = 0; rr < 2; ++rr)
#pragma unroll
        for (int r = 0; r < 4; ++r)
            trow[rr][r] = T[rowBase + rr * 16 + lhi * 4 + r];

    float acl[2][4] = {{0.f, 0.f, 0.f, 0.f}, {0.f, 0.f, 0.f, 0.f}};
    for (int t = 0; t < CPW / 16; ++t) {
        const int bcol = colBase0 + t * 16 + llo;
        bf16x8 b[4];
#pragma unroll
        for (int kb = 0; kb < 4; ++kb)
            b[kb] = *reinterpret_cast<const bf16x8*>(
                E + (size_t)bcol * D + kb * 32 + lhi * 8);
        const int tcol = T[bcol];
#pragma unroll
        for (int rr = 0; rr < 2; ++rr) {
            f32x4 acc = {0.f, 0.f, 0.f, 0.f};
#pragma unroll
            for (int kb = 0; kb < 4; ++kb)
                acc = __builtin_amdgcn_mfma_f32_16x16x32_bf16(a[rr][kb], b[kb], acc, 0, 0, 0);
#pragma unroll
            for (int r = 0; r < 4; ++r) {
                const float sv = acc[r];
                const int rowG = rowBase + rr * 16 + lhi * 4 + r;
                if (tcol == trow[rr][r]) {
                    if (rowG != bcol && sv < thrP[rr][r]) acl[rr][r] += 1.0f - sv;
                } else {
                    if (sv > thrN[rr][r]) acl[rr][r] += sv;
                }
            }
        }
    }
    float tot = 0.f;
#pragma unroll
    for (int rr = 0; rr < 2; ++rr)
#pragma unroll
        for (int r = 0; r < 4; ++r) tot += acl[rr][r] * hasPos[rr][r];
#pragma unroll
    for (int off = 1; off < 64; off <<= 1) tot += __shfl_xor(tot, off);

    __shared__ float wsum[4];
    if (lane == 0) wsum[wave] = tot;
    __syncthreads();
    if (threadIdx.x == 0)
        atomicAdd(out, (wsum[0] + wsum[1] + wsum[2] + wsum[3]) * (1.0f / 12288.0f));
}

extern "C" void kernel_launch(void* const* d_in, const int* in_sizes, int n_in,
                              void* d_out, int out_size, void* d_ws, size_t ws_size,
                              hipStream_t stream) {
    const float* emb = (const float*)d_in[0];
    const int* tgt = (const int*)d_in[1];
    float* out = (float*)d_out;

    unsigned short* ebf = (unsigned short*)d_ws;            // 3 MiB bf16 copy
    float* wsmax = (float*)((char*)d_ws + (size_t)SUBSETS * M * D * 2);  // 1.5 MiB partial maxes

    const int n = SUBSETS * M * D;
    const int n8 = n / 8;

    hipMemsetAsync(out, 0, sizeof(float), stream);
    cvt_f32_bf16<<<n8 / 256, 256, 0, stream>>>(emb, ebf, n8);
    pass_max<<<WGS, 256, 0, stream>>>(ebf, tgt, wsmax);
    pass_sum<<<WGS, 256, 0, stream>>>(ebf, tgt, wsmax, out);
}

// Round 5
// 130.294 us; speedup vs baseline: 1.8373x; 1.4366x over previous
//
#include <hip/hip_runtime.h>
#include <stdint.h>

typedef __bf16 bf16x8 __attribute__((ext_vector_type(8)));
typedef float f32x4 __attribute__((ext_vector_type(4)));
typedef unsigned short ushort8v __attribute__((ext_vector_type(8)));

static constexpr int SUBSETS = 3;
static constexpr int M = 4096;
static constexpr int D = 128;

static constexpr int WG_ROWS = 128;          // 4 waves x 32 rows
static constexpr int WG_COLS = 256;          // shared column strip per WG
static constexpr int NSTRIP = M / WG_COLS;   // 16
static constexpr int NRBWG = M / WG_ROWS;    // 32
static constexpr int WGS = SUBSETS * NRBWG * NSTRIP;  // 1536
static constexpr int SCOLS = 32;             // cols per LDS stage (8 KB)
static constexpr int NSTAGE = WG_COLS / SCOLS;        // 8

#define MARGIN_F 0.1f
#define NEGINF (-1e30f)

// ---------------- kernel 0: f32 -> bf16 (RNE) + zero the output scalar ----
__global__ void cvt_f32_bf16(const float* __restrict__ in,
                             unsigned short* __restrict__ out, int n8,
                             float* __restrict__ loss_out) {
    int i = blockIdx.x * blockDim.x + threadIdx.x;
    if (i == 0) *loss_out = 0.0f;   // pass_sum atomics run after us in-stream
    if (i >= n8) return;
    const float4* p = reinterpret_cast<const float4*>(in) + (size_t)i * 2;
    float4 a = p[0];
    float4 b = p[1];
    float v[8] = {a.x, a.y, a.z, a.w, b.x, b.y, b.z, b.w};
    ushort8v r;
#pragma unroll
    for (int j = 0; j < 8; ++j) {
        uint32_t u = __builtin_bit_cast(uint32_t, v[j]);
        u = (u + 0x7FFFu + ((u >> 16) & 1u)) >> 16;  // RNE to bf16
        r[j] = (unsigned short)u;
    }
    *(reinterpret_cast<ushort8v*>(out) + i) = r;
}

// Stage SCOLS=32 cols (8 KB) of B into LDS, coalesced, with inverse-swizzled
// per-lane global source so that swizzled ds_read is conflict-free (rule #21).
// LDS[col*256 + (off ^ ((col&7)<<4))] = B[colBase+col][off]
__device__ __forceinline__ void stage_tile(const unsigned short* __restrict__ base,
                                           unsigned short* __restrict__ ldsbuf,
                                           int w, int lane) {
#pragma unroll
    for (int i = 0; i < 2; ++i) {
        const int slocal = w * 2048 + i * 1024 + lane * 16;  // byte slot in 8KB buf
        const int col = slocal >> 8;
        const int off = (slocal & 255) ^ ((col & 7) << 4);
        const char* gsrc = (const char*)base + col * 256 + off;
        char* ldst = (char*)ldsbuf + w * 2048 + i * 1024;    // wave-uniform base
        __builtin_amdgcn_global_load_lds(
            (const __attribute__((address_space(1))) void*)gsrc,
            (__attribute__((address_space(3))) void*)ldst,
            16, 0, 0);
    }
}

__device__ __forceinline__ bf16x8 lds_bfrag(const unsigned short* __restrict__ ldsbuf,
                                            int tt, int llo, int lhi, int kb) {
    const int col = tt * 16 + llo;
    const int off = (kb * 64 + lhi * 16) ^ ((col & 7) << 4);
    return *reinterpret_cast<const bf16x8*>((const char*)ldsbuf + col * 256 + off);
}

// ---------------- kernel 1: masked row maxes (pass 1) ----------------
__global__ __launch_bounds__(256) void pass_max(
        const unsigned short* __restrict__ ebf,
        const int* __restrict__ tgt,
        float* __restrict__ wsmax) {   // [2][SUBSETS][M][NSTRIP]
    __shared__ unsigned short lds[2][SCOLS * D];  // 2 x 8 KB

    const int wg = blockIdx.x;
    const int s = wg >> 9;          // /512
    const int rem = wg & 511;
    const int rbWG = rem & 31;
    const int cs = rem >> 5;

    const int tid = threadIdx.x;
    const int w = tid >> 6, lane = tid & 63;
    const int lhi = lane >> 4, llo = lane & 15;

    const unsigned short* E = ebf + (size_t)s * M * D;
    const int* T = tgt + s * M;
    const int rowBase = rbWG * WG_ROWS + w * 32;
    const int colBase = cs * WG_COLS;

    stage_tile(E + (size_t)colBase * D, lds[0], w, lane);

    // A fragments: 32 rows per wave
    bf16x8 a[2][4];
#pragma unroll
    for (int rr = 0; rr < 2; ++rr) {
        const int row = rowBase + rr * 16 + llo;
#pragma unroll
        for (int kb = 0; kb < 4; ++kb)
            a[rr][kb] = *reinterpret_cast<const bf16x8*>(
                E + (size_t)row * D + kb * 32 + lhi * 8);
    }
    int trow[2][4];
#pragma unroll
    for (int rr = 0; rr < 2; ++rr)
#pragma unroll
        for (int r = 0; r < 4; ++r)
            trow[rr][r] = T[rowBase + rr * 16 + lhi * 4 + r];

    float mp[2][4], mn[2][4];
#pragma unroll
    for (int rr = 0; rr < 2; ++rr)
#pragma unroll
        for (int r = 0; r < 4; ++r) { mp[rr][r] = NEGINF; mn[rr][r] = NEGINF; }

    __syncthreads();   // stage 0 landed (syncthreads drains vmcnt)

    for (int st = 0; st < NSTAGE; ++st) {
        const int buf = st & 1;
        if (st + 1 < NSTAGE)
            stage_tile(E + (size_t)(colBase + (st + 1) * SCOLS) * D, lds[buf ^ 1], w, lane);
#pragma unroll
        for (int tt = 0; tt < 2; ++tt) {
            const int bcol = colBase + st * SCOLS + tt * 16 + llo;
            bf16x8 b[4];
#pragma unroll
            for (int kb = 0; kb < 4; ++kb) b[kb] = lds_bfrag(lds[buf], tt, llo, lhi, kb);
            const int tcol = T[bcol];
#pragma unroll
            for (int rr = 0; rr < 2; ++rr) {
                f32x4 acc = {0.f, 0.f, 0.f, 0.f};
#pragma unroll
                for (int kb = 0; kb < 4; ++kb)
                    acc = __builtin_amdgcn_mfma_f32_16x16x32_bf16(a[rr][kb], b[kb], acc, 0, 0, 0);
#pragma unroll
                for (int r = 0; r < 4; ++r) {
                    const float sv = acc[r];
                    const int rowG = rowBase + rr * 16 + lhi * 4 + r;
                    if (tcol == trow[rr][r]) {
                        if (rowG != bcol) mp[rr][r] = fmaxf(mp[rr][r], sv);
                    } else {
                        mn[rr][r] = fmaxf(mn[rr][r], sv);
                    }
                }
            }
        }
        __syncthreads();   // drains vmcnt (next stage mostly landed) + buf reuse fence
    }

#pragma unroll
    for (int rr = 0; rr < 2; ++rr)
#pragma unroll
        for (int r = 0; r < 4; ++r) {
#pragma unroll
            for (int off = 1; off < 16; off <<= 1) {
                mp[rr][r] = fmaxf(mp[rr][r], __shfl_xor(mp[rr][r], off));
                mn[rr][r] = fmaxf(mn[rr][r], __shfl_xor(mn[rr][r], off));
            }
        }
    if (llo == 0) {
#pragma unroll
        for (int rr = 0; rr < 2; ++rr)
#pragma unroll
            for (int r = 0; r < 4; ++r) {
                const int row = rowBase + rr * 16 + lhi * 4 + r;
                wsmax[((size_t)(0 * SUBSETS + s) * M + row) * NSTRIP + cs] = mp[rr][r];
                wsmax[((size_t)(1 * SUBSETS + s) * M + row) * NSTRIP + cs] = mn[rr][r];
            }
    }
}

// ---------------- kernel 2: thresholded sums (pass 2) ----------------
__global__ __launch_bounds__(256) void pass_sum(
        const unsigned short* __restrict__ ebf,
        const int* __restrict__ tgt,
        const float* __restrict__ wsmax,
        float* __restrict__ out) {
    __shared__ unsigned short lds[2][SCOLS * D];
    __shared__ float wsum[4];

    const int wg = blockIdx.x;
    const int s = wg >> 9;
    const int rem = wg & 511;
    const int rbWG = rem & 31;
    const int cs = rem >> 5;

    const int tid = threadIdx.x;
    const int w = tid >> 6, lane = tid & 63;
    const int lhi = lane >> 4, llo = lane & 15;

    const unsigned short* E = ebf + (size_t)s * M * D;
    const int* T = tgt + s * M;
    const int rowBase = rbWG * WG_ROWS + w * 32;
    const int colBase = cs * WG_COLS;

    stage_tile(E + (size_t)colBase * D, lds[0], w, lane);

    // thresholds: lane llo reads strip llo's partial, reduce over 16 llo lanes
    float thrP[2][4], thrN[2][4], hasPos[2][4];
#pragma unroll
    for (int rr = 0; rr < 2; ++rr)
#pragma unroll
        for (int r = 0; r < 4; ++r) {
            const int row = rowBase + rr * 16 + lhi * 4 + r;
            float vp = wsmax[((size_t)(0 * SUBSETS + s) * M + row) * NSTRIP + llo];
            float vn = wsmax[((size_t)(1 * SUBSETS + s) * M + row) * NSTRIP + llo];
#pragma unroll
            for (int off = 1; off < 16; off <<= 1) {
                vp = fmaxf(vp, __shfl_xor(vp, off));
                vn = fmaxf(vn, __shfl_xor(vn, off));
            }
            thrP[rr][r] = vn + MARGIN_F;
            thrN[rr][r] = fmaxf(0.6f, vp) - MARGIN_F;
            hasPos[rr][r] = (vp > -1e29f) ? 1.0f : 0.0f;
        }

    bf16x8 a[2][4];
#pragma unroll
    for (int rr = 0; rr < 2; ++rr) {
        const int row = rowBase + rr * 16 + llo;
#pragma unroll
        for (int kb = 0; kb < 4; ++kb)
            a[rr][kb] = *reinterpret_cast<const bf16x8*>(
                E + (size_t)row * D + kb * 32 + lhi * 8);
    }
    int trow[2][4];
#pragma unroll
    for (int rr = 0; rr < 2; ++rr)
#pragma unroll
        for (int r = 0; r < 4; ++r)
            trow[rr][r] = T[rowBase + rr * 16 + lhi * 4 + r];

    float acl[2][4] = {{0.f, 0.f, 0.f, 0.f}, {0.f, 0.f, 0.f, 0.f}};

    __syncthreads();   // stage 0 landed

    for (int st = 0; st < NSTAGE; ++st) {
        const int buf = st & 1;
        if (st + 1 < NSTAGE)
            stage_tile(E + (size_t)(colBase + (st + 1) * SCOLS) * D, lds[buf ^ 1], w, lane);
#pragma unroll
        for (int tt = 0; tt < 2; ++tt) {
            const int bcol = colBase + st * SCOLS + tt * 16 + llo;
            bf16x8 b[4];
#pragma unroll
            for (int kb = 0; kb < 4; ++kb) b[kb] = lds_bfrag(lds[buf], tt, llo, lhi, kb);
            const int tcol = T[bcol];
#pragma unroll
            for (int rr = 0; rr < 2; ++rr) {
                f32x4 acc = {0.f, 0.f, 0.f, 0.f};
#pragma unroll
                for (int kb = 0; kb < 4; ++kb)
                    acc = __builtin_amdgcn_mfma_f32_16x16x32_bf16(a[rr][kb], b[kb], acc, 0, 0, 0);
#pragma unroll
                for (int r = 0; r < 4; ++r) {
                    const float sv = acc[r];
                    const int rowG = rowBase + rr * 16 + lhi * 4 + r;
                    if (tcol == trow[rr][r]) {
                        if (rowG != bcol && sv < thrP[rr][r]) acl[rr][r] += 1.0f - sv;
                    } else {
                        if (sv > thrN[rr][r]) acl[rr][r] += sv;
                    }
                }
            }
        }
        __syncthreads();
    }

    float tot = 0.f;
#pragma unroll
    for (int rr = 0; rr < 2; ++rr)
#pragma unroll
        for (int r = 0; r < 4; ++r) tot += acl[rr][r] * hasPos[rr][r];
#pragma unroll
    for (int off = 1; off < 64; off <<= 1) tot += __shfl_xor(tot, off);

    if (lane == 0) wsum[w] = tot;
    __syncthreads();
    if (tid == 0)
        atomicAdd(out, (wsum[0] + wsum[1] + wsum[2] + wsum[3]) * (1.0f / 12288.0f));
}

extern "C" void kernel_launch(void* const* d_in, const int* in_sizes, int n_in,
                              void* d_out, int out_size, void* d_ws, size_t ws_size,
                              hipStream_t stream) {
    const float* emb = (const float*)d_in[0];
    const int* tgt = (const int*)d_in[1];
    float* out = (float*)d_out;

    unsigned short* ebf = (unsigned short*)d_ws;            // 3 MiB bf16 copy
    float* wsmax = (float*)((char*)d_ws + (size_t)SUBSETS * M * D * 2);  // partial maxes

    const int n = SUBSETS * M * D;
    const int n8 = n / 8;

    cvt_f32_bf16<<<n8 / 256, 256, 0, stream>>>(emb, ebf, n8, out);
    pass_max<<<WGS, 256, 0, stream>>>(ebf, tgt, wsmax);
    pass_sum<<<WGS, 256, 0, stream>>>(ebf, tgt, wsmax, out);
}

// Round 6
// 126.179 us; speedup vs baseline: 1.8972x; 1.0326x over previous
//
#include <hip/hip_runtime.h>
#include <stdint.h>

typedef __bf16 bf16x8 __attribute__((ext_vector_type(8)));
typedef float f32x4 __attribute__((ext_vector_type(4)));
typedef unsigned short ushort8v __attribute__((ext_vector_type(8)));

static constexpr int SUBSETS = 3;
static constexpr int M = 4096;
static constexpr int D = 128;

static constexpr int WG_ROWS = 256;          // 4 waves x 64 rows
static constexpr int WG_COLS = 256;          // shared column strip per WG
static constexpr int NSTRIP = M / WG_COLS;   // 16
static constexpr int NPANEL = M / WG_ROWS;   // 16
static constexpr int WGS = SUBSETS * NPANEL * NSTRIP;  // 768  (3 WGs/CU)
static constexpr int SCOLS = 32;             // cols per LDS stage (8 KB)
static constexpr int NSTAGE = WG_COLS / SCOLS;        // 8

#define MARGIN_F 0.1f
#define NEGINF (-1e30f)
#define POSINF (1e30f)

// ---------------- kernel 0: f32 -> bf16 (RNE) + zero the output scalar ----
__global__ void cvt_f32_bf16(const float* __restrict__ in,
                             unsigned short* __restrict__ out, int n8,
                             float* __restrict__ loss_out) {
    int i = blockIdx.x * blockDim.x + threadIdx.x;
    if (i == 0) *loss_out = 0.0f;   // pass_sum atomics run after us in-stream
    if (i >= n8) return;
    const float4* p = reinterpret_cast<const float4*>(in) + (size_t)i * 2;
    float4 a = p[0];
    float4 b = p[1];
    float v[8] = {a.x, a.y, a.z, a.w, b.x, b.y, b.z, b.w};
    ushort8v r;
#pragma unroll
    for (int j = 0; j < 8; ++j) {
        uint32_t u = __builtin_bit_cast(uint32_t, v[j]);
        u = (u + 0x7FFFu + ((u >> 16) & 1u)) >> 16;  // RNE to bf16
        r[j] = (unsigned short)u;
    }
    *(reinterpret_cast<ushort8v*>(out) + i) = r;
}

// Stage SCOLS=32 cols (8 KB) of B into LDS, coalesced, with inverse-swizzled
// per-lane global source so the swizzled ds_read is conflict-free (rule #21).
// LDS[col*256 + (off ^ ((col&7)<<4))] = B[colBase+col][off]
__device__ __forceinline__ void stage_tile(const unsigned short* __restrict__ base,
                                           unsigned short* __restrict__ ldsbuf,
                                           int w, int lane) {
#pragma unroll
    for (int i = 0; i < 2; ++i) {
        const int slocal = w * 2048 + i * 1024 + lane * 16;  // byte slot in 8KB buf
        const int col = slocal >> 8;
        const int off = (slocal & 255) ^ ((col & 7) << 4);
        const char* gsrc = (const char*)base + col * 256 + off;
        char* ldst = (char*)ldsbuf + w * 2048 + i * 1024;    // wave-uniform base
        __builtin_amdgcn_global_load_lds(
            (const __attribute__((address_space(1))) void*)gsrc,
            (__attribute__((address_space(3))) void*)ldst,
            16, 0, 0);
    }
}

__device__ __forceinline__ bf16x8 lds_bfrag(const unsigned short* __restrict__ ldsbuf,
                                            int tt, int llo, int lhi, int kb) {
    const int col = tt * 16 + llo;
    const int off = (kb * 64 + lhi * 16) ^ ((col & 7) << 4);
    return *reinterpret_cast<const bf16x8*>((const char*)ldsbuf + col * 256 + off);
}

// ---------------- kernel 1: masked row maxes (pass 1) ----------------
__global__ __launch_bounds__(256) void pass_max(
        const unsigned short* __restrict__ ebf,
        const int* __restrict__ tgt,
        float* __restrict__ wsmax) {   // [2][SUBSETS][M][NSTRIP]
    __shared__ unsigned short lds[2][SCOLS * D];  // 2 x 8 KB

    const int wg = blockIdx.x;
    const int s = wg >> 8;          // /256
    const int rem = wg & 255;
    const int panel = rem & (NPANEL - 1);
    const int cs = rem >> 4;

    const int tid = threadIdx.x;
    const int w = tid >> 6, lane = tid & 63;
    const int lhi = lane >> 4, llo = lane & 15;

    const unsigned short* E = ebf + (size_t)s * M * D;
    const int* T = tgt + s * M;
    const int rowBase = panel * WG_ROWS + w * 64;
    const int colBase = cs * WG_COLS;

    stage_tile(E + (size_t)colBase * D, lds[0], w, lane);

    // A fragments: 64 rows per wave (4 MFMA row-blocks)
    bf16x8 a[4][4];
#pragma unroll
    for (int rr = 0; rr < 4; ++rr) {
        const int row = rowBase + rr * 16 + llo;
#pragma unroll
        for (int kb = 0; kb < 4; ++kb)
            a[rr][kb] = *reinterpret_cast<const bf16x8*>(
                E + (size_t)row * D + kb * 32 + lhi * 8);
    }
    int trow[4][4];
#pragma unroll
    for (int rr = 0; rr < 4; ++rr)
#pragma unroll
        for (int r = 0; r < 4; ++r)
            trow[rr][r] = T[rowBase + rr * 16 + lhi * 4 + r];

    float mp[4][4], mn[4][4];
#pragma unroll
    for (int rr = 0; rr < 4; ++rr)
#pragma unroll
        for (int r = 0; r < 4; ++r) { mp[rr][r] = NEGINF; mn[rr][r] = NEGINF; }

    __syncthreads();   // stage 0 landed (syncthreads drains vmcnt)

    for (int st = 0; st < NSTAGE; ++st) {
        const int buf = st & 1;
        if (st + 1 < NSTAGE)
            stage_tile(E + (size_t)(colBase + (st + 1) * SCOLS) * D, lds[buf ^ 1], w, lane);
#pragma unroll
        for (int tt = 0; tt < 2; ++tt) {
            const int bcol = colBase + st * SCOLS + tt * 16 + llo;
            bf16x8 b[4];
#pragma unroll
            for (int kb = 0; kb < 4; ++kb) b[kb] = lds_bfrag(lds[buf], tt, llo, lhi, kb);
            const int tcol = T[bcol];
#pragma unroll
            for (int rr = 0; rr < 4; ++rr) {
                f32x4 acc = {0.f, 0.f, 0.f, 0.f};
#pragma unroll
                for (int kb = 0; kb < 4; ++kb)
                    acc = __builtin_amdgcn_mfma_f32_16x16x32_bf16(a[rr][kb], b[kb], acc, 0, 0, 0);
#pragma unroll
                for (int r = 0; r < 4; ++r) {
                    const float sv = acc[r];
                    const int rowG = rowBase + rr * 16 + lhi * 4 + r;
                    const bool same = (tcol == trow[rr][r]);
                    const bool offd = (rowG != bcol);
                    // branchless masked maxes
                    mp[rr][r] = fmaxf(mp[rr][r], (same && offd) ? sv : NEGINF);
                    mn[rr][r] = fmaxf(mn[rr][r], same ? NEGINF : sv);
                }
            }
        }
        __syncthreads();   // buf reuse fence; drains staging vmcnt
    }

#pragma unroll
    for (int rr = 0; rr < 4; ++rr)
#pragma unroll
        for (int r = 0; r < 4; ++r) {
#pragma unroll
            for (int off = 1; off < 16; off <<= 1) {
                mp[rr][r] = fmaxf(mp[rr][r], __shfl_xor(mp[rr][r], off));
                mn[rr][r] = fmaxf(mn[rr][r], __shfl_xor(mn[rr][r], off));
            }
        }
    if (llo == 0) {
#pragma unroll
        for (int rr = 0; rr < 4; ++rr)
#pragma unroll
            for (int r = 0; r < 4; ++r) {
                const int row = rowBase + rr * 16 + lhi * 4 + r;
                wsmax[((size_t)(0 * SUBSETS + s) * M + row) * NSTRIP + cs] = mp[rr][r];
                wsmax[((size_t)(1 * SUBSETS + s) * M + row) * NSTRIP + cs] = mn[rr][r];
            }
    }
}

// ---------------- kernel 2: thresholded sums (pass 2) ----------------
__global__ __launch_bounds__(256) void pass_sum(
        const unsigned short* __restrict__ ebf,
        const int* __restrict__ tgt,
        const float* __restrict__ wsmax,
        float* __restrict__ out) {
    __shared__ unsigned short lds[2][SCOLS * D];
    __shared__ float wsum[4];

    const int wg = blockIdx.x;
    const int s = wg >> 8;
    const int rem = wg & 255;
    const int panel = rem & (NPANEL - 1);
    const int cs = rem >> 4;

    const int tid = threadIdx.x;
    const int w = tid >> 6, lane = tid & 63;
    const int lhi = lane >> 4, llo = lane & 15;

    const unsigned short* E = ebf + (size_t)s * M * D;
    const int* T = tgt + s * M;
    const int rowBase = panel * WG_ROWS + w * 64;
    const int colBase = cs * WG_COLS;

    stage_tile(E + (size_t)colBase * D, lds[0], w, lane);

    // thresholds: lane llo reads strip llo's partial, reduce over 16 llo lanes.
    // hasPos folded in: no positive -> thrP=-inf (select none), thrN=+inf (select none).
    float thrP[4][4], thrN[4][4];
#pragma unroll
    for (int rr = 0; rr < 4; ++rr)
#pragma unroll
        for (int r = 0; r < 4; ++r) {
            const int row = rowBase + rr * 16 + lhi * 4 + r;
            float vp = wsmax[((size_t)(0 * SUBSETS + s) * M + row) * NSTRIP + llo];
            float vn = wsmax[((size_t)(1 * SUBSETS + s) * M + row) * NSTRIP + llo];
#pragma unroll
            for (int off = 1; off < 16; off <<= 1) {
                vp = fmaxf(vp, __shfl_xor(vp, off));
                vn = fmaxf(vn, __shfl_xor(vn, off));
            }
            const bool hasPos = (vp > -1e29f);
            thrP[rr][r] = hasPos ? vn + MARGIN_F : NEGINF;
            thrN[rr][r] = hasPos ? fmaxf(0.6f, vp) - MARGIN_F : POSINF;
        }

    bf16x8 a[4][4];
#pragma unroll
    for (int rr = 0; rr < 4; ++rr) {
        const int row = rowBase + rr * 16 + llo;
#pragma unroll
        for (int kb = 0; kb < 4; ++kb)
            a[rr][kb] = *reinterpret_cast<const bf16x8*>(
                E + (size_t)row * D + kb * 32 + lhi * 8);
    }
    int trow[4][4];
#pragma unroll
    for (int rr = 0; rr < 4; ++rr)
#pragma unroll
        for (int r = 0; r < 4; ++r)
            trow[rr][r] = T[rowBase + rr * 16 + lhi * 4 + r];

    float acl[4][4];
#pragma unroll
    for (int rr = 0; rr < 4; ++rr)
#pragma unroll
        for (int r = 0; r < 4; ++r) acl[rr][r] = 0.f;

    __syncthreads();   // stage 0 landed

    for (int st = 0; st < NSTAGE; ++st) {
        const int buf = st & 1;
        if (st + 1 < NSTAGE)
            stage_tile(E + (size_t)(colBase + (st + 1) * SCOLS) * D, lds[buf ^ 1], w, lane);
#pragma unroll
        for (int tt = 0; tt < 2; ++tt) {
            const int bcol = colBase + st * SCOLS + tt * 16 + llo;
            bf16x8 b[4];
#pragma unroll
            for (int kb = 0; kb < 4; ++kb) b[kb] = lds_bfrag(lds[buf], tt, llo, lhi, kb);
            const int tcol = T[bcol];
#pragma unroll
            for (int rr = 0; rr < 4; ++rr) {
                f32x4 acc = {0.f, 0.f, 0.f, 0.f};
#pragma unroll
                for (int kb = 0; kb < 4; ++kb)
                    acc = __builtin_amdgcn_mfma_f32_16x16x32_bf16(a[rr][kb], b[kb], acc, 0, 0, 0);
#pragma unroll
                for (int r = 0; r < 4; ++r) {
                    const float sv = acc[r];
                    const int rowG = rowBase + rr * 16 + lhi * 4 + r;
                    const bool same = (tcol == trow[rr][r]);
                    const bool offd = (rowG != bcol);
                    // branchless selection
                    const float addp = (same && offd && (sv < thrP[rr][r])) ? (1.0f - sv) : 0.0f;
                    const float addn = (!same && (sv > thrN[rr][r])) ? sv : 0.0f;
                    acl[rr][r] += addp + addn;
                }
            }
        }
        __syncthreads();
    }

    float tot = 0.f;
#pragma unroll
    for (int rr = 0; rr < 4; ++rr)
#pragma unroll
        for (int r = 0; r < 4; ++r) tot += acl[rr][r];
#pragma unroll
    for (int off = 1; off < 64; off <<= 1) tot += __shfl_xor(tot, off);

    if (lane == 0) wsum[w] = tot;
    __syncthreads();
    if (tid == 0)
        atomicAdd(out, (wsum[0] + wsum[1] + wsum[2] + wsum[3]) * (1.0f / 12288.0f));
}

extern "C" void kernel_launch(void* const* d_in, const int* in_sizes, int n_in,
                              void* d_out, int out_size, void* d_ws, size_t ws_size,
                              hipStream_t stream) {
    const float* emb = (const float*)d_in[0];
    const int* tgt = (const int*)d_in[1];
    float* out = (float*)d_out;

    unsigned short* ebf = (unsigned short*)d_ws;            // 3 MiB bf16 copy
    float* wsmax = (float*)((char*)d_ws + (size_t)SUBSETS * M * D * 2);  // partial maxes

    const int n = SUBSETS * M * D;
    const int n8 = n / 8;

    cvt_f32_bf16<<<n8 / 256, 256, 0, stream>>>(emb, ebf, n8, out);
    pass_max<<<WGS, 256, 0, stream>>>(ebf, tgt, wsmax);
    pass_sum<<<WGS, 256, 0, stream>>>(ebf, tgt, wsmax, out);
}